// Round 7
// baseline (104.220 us; speedup 1.0000x reference)
//
#include <hip/hip_runtime.h>

// Problem constants (fixed by the reference)
constexpr int B_N   = 2048;
constexpr int C_N   = 32;
constexpr int SD    = 64;    // STATE_DIM
constexpr int EMB   = 256;
constexpr int OUTD  = 256;
constexpr int OBSD  = 512;
constexpr int XDIM  = 512;   // concat dim
constexpr int CAP   = 256;   // per-category row capacity (mean 64, ~96 at 4 sigma)

typedef __attribute__((ext_vector_type(8))) short bf16x8;
typedef __attribute__((ext_vector_type(4))) short bf16x4;
typedef __attribute__((ext_vector_type(4))) float f32x4;

// ws layout (bytes):
//   0        : int counts[32]
//   4096     : int rows[32][CAP]            (32 KB)
//   65536    : packed obs_W   bf16          (256 KB)
//   327680   : packed state_W bf16          (1 MB)
//   1376256  : packed l2_W    bf16          (8 MB)
constexpr size_t OFF_ROWS  = 4096;
constexpr size_t OFF_POBS  = 65536;
constexpr size_t OFF_PSTAT = 327680;
constexpr size_t OFF_PL2   = 1376256;
constexpr size_t NEED_L2   = OFF_PL2 + (size_t)C_N * XDIM * OUTD * 2;

__device__ __forceinline__ unsigned short bf_cvt(float f) {
    union { float f; unsigned u; } x; x.f = f;
    unsigned r = x.u + 0x7FFF + ((x.u >> 16) & 1);   // RNE
    return (unsigned short)(r >> 16);
}

// Fragment layout (B-operand of mfma_f32_16x16x32_bf16), per K-chunk of 32:
//   p[((chunk*16 + strip)*64 + lane)*8 + j] = W[chunk*32 + (lane>>4)*8 + j][strip*16 + (lane&15)]
__global__ __launch_bounds__(256) void prep_kernel(
    const int* __restrict__ cat_ids,
    const float* __restrict__ obs_W, const float* __restrict__ state_W,
    const float* __restrict__ l2_W,
    int* __restrict__ counts, int* __restrict__ rows,
    unsigned short* __restrict__ p_obs, unsigned short* __restrict__ p_state,
    unsigned short* __restrict__ p_l2, int do_l2) {
    const int bid = blockIdx.x;
    const int t = threadIdx.x;

    if (bid < C_N) {
        // ---- bucket for category c = bid ----
        __shared__ int cnt;
        __shared__ int list[CAP];
        if (t == 0) cnt = 0;
        __syncthreads();
        const int c = bid;
        for (int r = t; r < B_N; r += 256) {
            if (cat_ids[r] == c) {
                int s = atomicAdd(&cnt, 1);
                if (s < CAP) list[s] = r;
            }
        }
        __syncthreads();
        int n = min(cnt, CAP);
        for (int s = t; s < n; s += 256) rows[c * CAP + s] = list[s];
        if (t == 0) counts[c] = n;
        return;
    }

    // ---- pack one 32-row K-chunk of one weight matrix ----
    const float* src;
    unsigned short* dst;
    {
        int pb = bid - C_N;
        if (pb < 16) {                       // obs_W, chunk = pb
            src = obs_W + (size_t)pb * 32 * 256;
            dst = p_obs + (size_t)pb * 8192;
        } else if (pb < 80) {                // state_W: i = mat*2 + chunk
            int i = pb - 16;
            int mat = i >> 1, ch = i & 1;
            src = state_W + ((size_t)mat * SD + ch * 32) * 256;
            dst = p_state + (size_t)i * 8192;
        } else {                             // l2_W: i = mat*16 + chunk
            if (!do_l2) return;
            int i = pb - 80;
            int mat = i >> 4, ch = i & 15;
            src = l2_W + ((size_t)mat * XDIM + ch * 32) * 256;
            dst = p_l2 + (size_t)i * 8192;
        }
    }

    __shared__ __align__(16) unsigned short sW[32 * 264];   // 32 rows, pad 256->264
    #pragma unroll
    for (int i2 = 0; i2 < 8; ++i2) {
        int f = t + 256 * i2;                // float4 index in contiguous 32x256 block
        int row = f >> 6, c4 = f & 63;
        float4 v = ((const float4*)src)[f];
        unsigned short* d = &sW[row * 264 + c4 * 4];
        d[0] = bf_cvt(v.x); d[1] = bf_cvt(v.y); d[2] = bf_cvt(v.z); d[3] = bf_cvt(v.w);
    }
    __syncthreads();
    #pragma unroll
    for (int s4 = 0; s4 < 4; ++s4) {
        int slot = s4 * 256 + t;             // (strip,lane) slot, 1024 total
        int strip = slot >> 6, lane = slot & 63;
        int r0 = (lane >> 4) * 8, col = strip * 16 + (lane & 15);
        unsigned short v[8];
        #pragma unroll
        for (int j = 0; j < 8; ++j) v[j] = sW[(r0 + j) * 264 + col];
        *(bf16x8*)(dst + (size_t)slot * 8) = *(bf16x8*)v;
    }
}

// One block per (cat, 32-row tile) = two 16-row MFMA m-tiles. 512 threads =
// 8 waves; wave w owns col strips {2w, 2w+1}. Each b-fragment feeds 2 MFMAs.
__global__ __launch_bounds__(512) void fused_kernel(
    const float* __restrict__ state, const float* __restrict__ obs,
    const float* __restrict__ obs_b, const float* __restrict__ state_b,
    const float* __restrict__ l2_W, const float* __restrict__ l2_b,
    const int* __restrict__ counts, const int* __restrict__ rows,
    const unsigned short* __restrict__ p_obs,
    const unsigned short* __restrict__ p_state,
    const unsigned short* __restrict__ p_l2, int has_pl2,
    float* __restrict__ out) {
    const int c = blockIdx.x;
    const int tile = blockIdx.y;
    const int n = counts[c];
    const int rbase = tile * 32;
    if (rbase >= n) return;
    const int nr = min(32, n - rbase);

    __shared__ __align__(16) unsigned short sAs[32 * 72];    // state rows (pad 64->72)
    __shared__ __align__(16) unsigned short sAo[32 * 520];   // obs rows (pad 512->520)
    __shared__ __align__(16) unsigned short sX[32 * 520];    // x rows (pad 512->520)
    __shared__ int sRows[32];

    const int t = threadIdx.x;
    const int w = t >> 6, l = t & 63;
    const int ml = l & 15, quad = l >> 4;
    const int* rowp = rows + c * CAP + rbase;

    // ---- Prefetch phase-1 (all 4) and phase-2 (first 6 chunks) b-fragments.
    //      These loads drain during the gather -> free overlap.
    const bf16x8* pb1 = (const bf16x8*)(p_state + (size_t)c * SD * 256);
    const bf16x8* pb2 = (const bf16x8*)p_obs;
    bf16x8 pf1[4], pf2[12];
    #pragma unroll
    for (int kk = 0; kk < 2; ++kk)
        #pragma unroll
        for (int si = 0; si < 2; ++si)
            pf1[kk * 2 + si] = pb1[(kk * 16 + w * 2 + si) * 64 + l];
    #pragma unroll
    for (int kk = 0; kk < 6; ++kk)
        #pragma unroll
        for (int si = 0; si < 2; ++si)
            pf2[kk * 2 + si] = pb2[(kk * 16 + w * 2 + si) * 64 + l];

    // Stage row ids for the epilogue (visible after the post-gather barrier;
    // no extra barrier needed here — gather reads rows[] directly).
    if (t < 32) sRows[t] = (t < nr) ? rowp[t] : 0;

    // Gather + fp32->bf16 (coalesced float4; rows >= nr zeroed)
    {   // state: 32 rows x 16 float4 = 512 slots, 1 per thread
        int i = t >> 4, c4 = t & 15;
        unsigned short vv[4] = {0, 0, 0, 0};
        if (i < nr) {
            int ridx = rowp[i];
            float4 v = ((const float4*)(state + (size_t)ridx * SD))[c4];
            vv[0] = bf_cvt(v.x); vv[1] = bf_cvt(v.y); vv[2] = bf_cvt(v.z); vv[3] = bf_cvt(v.w);
        }
        *(bf16x4*)&sAs[i * 72 + c4 * 4] = *(bf16x4*)vv;
    }
    #pragma unroll
    for (int i2 = 0; i2 < 8; ++i2) {         // obs: 32 rows x 128 float4 = 4096 slots
        int f = t + 512 * i2;
        int i = f >> 7, c4 = f & 127;
        unsigned short vv[4] = {0, 0, 0, 0};
        if (i < nr) {
            int ridx = rowp[i];
            float4 v = ((const float4*)(obs + (size_t)ridx * OBSD))[c4];
            vv[0] = bf_cvt(v.x); vv[1] = bf_cvt(v.y); vv[2] = bf_cvt(v.z); vv[3] = bf_cvt(v.w);
        }
        *(bf16x4*)&sAo[i * 520 + c4 * 4] = *(bf16x4*)vv;
    }
    __syncthreads();

    // ---- Phase 1: state_emb = relu(A_s x state_W[c] + b)  (K=64: 2 chunks) ----
    {
        f32x4 acc[2][2];
        #pragma unroll
        for (int mt = 0; mt < 2; ++mt)
            #pragma unroll
            for (int si = 0; si < 2; ++si) acc[mt][si] = (f32x4){0.f, 0.f, 0.f, 0.f};
        #pragma unroll
        for (int kk = 0; kk < 2; ++kk) {
            #pragma unroll
            for (int mt = 0; mt < 2; ++mt) {
                bf16x8 a = *(const bf16x8*)&sAs[(mt * 16 + ml) * 72 + kk * 32 + quad * 8];
                #pragma unroll
                for (int si = 0; si < 2; ++si)
                    acc[mt][si] = __builtin_amdgcn_mfma_f32_16x16x32_bf16(a, pf1[kk * 2 + si], acc[mt][si], 0, 0, 0);
            }
        }
        #pragma unroll
        for (int si = 0; si < 2; ++si) {
            int colb = (w * 2 + si) * 16 + ml;
            float bias = state_b[c * 256 + colb];
            #pragma unroll
            for (int mt = 0; mt < 2; ++mt)
                #pragma unroll
                for (int r = 0; r < 4; ++r)
                    sX[(mt * 16 + quad * 4 + r) * 520 + colb] = bf_cvt(fmaxf(acc[mt][si][r] + bias, 0.f));
        }
    }

    // ---- Phase 2: obs_emb = A_o x obs_W + b  (K=512: 16 chunks, ring depth 6) ----
    {
        f32x4 acc[2][2];
        #pragma unroll
        for (int mt = 0; mt < 2; ++mt)
            #pragma unroll
            for (int si = 0; si < 2; ++si) acc[mt][si] = (f32x4){0.f, 0.f, 0.f, 0.f};
        #pragma unroll
        for (int kk = 0; kk < 16; ++kk) {
            bf16x8 a0 = *(const bf16x8*)&sAo[ml * 520 + kk * 32 + quad * 8];
            bf16x8 a1 = *(const bf16x8*)&sAo[(16 + ml) * 520 + kk * 32 + quad * 8];
            #pragma unroll
            for (int si = 0; si < 2; ++si) {
                int slot = (kk % 6) * 2 + si;
                bf16x8 b = pf2[slot];
                if (kk < 10)
                    pf2[slot] = pb2[((kk + 6) * 16 + w * 2 + si) * 64 + l];
                acc[0][si] = __builtin_amdgcn_mfma_f32_16x16x32_bf16(a0, b, acc[0][si], 0, 0, 0);
                acc[1][si] = __builtin_amdgcn_mfma_f32_16x16x32_bf16(a1, b, acc[1][si], 0, 0, 0);
            }
        }
        #pragma unroll
        for (int si = 0; si < 2; ++si) {
            int colb = (w * 2 + si) * 16 + ml;
            float bias = obs_b[colb];
            #pragma unroll
            for (int mt = 0; mt < 2; ++mt)
                #pragma unroll
                for (int r = 0; r < 4; ++r)
                    sX[(mt * 16 + quad * 4 + r) * 520 + 256 + colb] = bf_cvt(acc[mt][si][r] + bias);
        }
    }

    // ---- Prefetch phase-3 first 6 chunks BEFORE the sX barrier ----
    const bf16x8* pb3 = (const bf16x8*)p_l2 + (size_t)c * 16384;
    bf16x8 pf3[12];
    if (has_pl2) {
        #pragma unroll
        for (int kk = 0; kk < 6; ++kk)
            #pragma unroll
            for (int si = 0; si < 2; ++si)
                pf3[kk * 2 + si] = pb3[(kk * 16 + w * 2 + si) * 64 + l];
    }
    __syncthreads();

    // ---- Phase 3: out = x @ l2_W[c] + b  (K=512: 16 chunks, ring depth 6) ----
    {
        f32x4 acc[2][2];
        #pragma unroll
        for (int mt = 0; mt < 2; ++mt)
            #pragma unroll
            for (int si = 0; si < 2; ++si) acc[mt][si] = (f32x4){0.f, 0.f, 0.f, 0.f};
        if (has_pl2) {
            #pragma unroll
            for (int kk = 0; kk < 16; ++kk) {
                bf16x8 a0 = *(const bf16x8*)&sX[ml * 520 + kk * 32 + quad * 8];
                bf16x8 a1 = *(const bf16x8*)&sX[(16 + ml) * 520 + kk * 32 + quad * 8];
                #pragma unroll
                for (int si = 0; si < 2; ++si) {
                    int slot = (kk % 6) * 2 + si;
                    bf16x8 b = pf3[slot];
                    if (kk < 10)
                        pf3[slot] = pb3[((kk + 6) * 16 + w * 2 + si) * 64 + l];
                    acc[0][si] = __builtin_amdgcn_mfma_f32_16x16x32_bf16(a0, b, acc[0][si], 0, 0, 0);
                    acc[1][si] = __builtin_amdgcn_mfma_f32_16x16x32_bf16(a1, b, acc[1][si], 0, 0, 0);
                }
            }
        } else {
            for (int kk = 0; kk < 16; ++kk) {
                bf16x8 a0 = *(const bf16x8*)&sX[ml * 520 + kk * 32 + quad * 8];
                bf16x8 a1 = *(const bf16x8*)&sX[(16 + ml) * 520 + kk * 32 + quad * 8];
                #pragma unroll
                for (int si = 0; si < 2; ++si) {
                    const float* wsrc = l2_W + ((size_t)c * XDIM + kk * 32 + quad * 8) * 256
                                        + (w * 2 + si) * 16 + ml;
                    bf16x8 b;
                    #pragma unroll
                    for (int j = 0; j < 8; ++j) b[j] = (short)bf_cvt(wsrc[j * 256]);
                    acc[0][si] = __builtin_amdgcn_mfma_f32_16x16x32_bf16(a0, b, acc[0][si], 0, 0, 0);
                    acc[1][si] = __builtin_amdgcn_mfma_f32_16x16x32_bf16(a1, b, acc[1][si], 0, 0, 0);
                }
            }
        }
        #pragma unroll
        for (int si = 0; si < 2; ++si) {
            int colb = (w * 2 + si) * 16 + ml;
            float bias = l2_b[c * 256 + colb];
            #pragma unroll
            for (int mt = 0; mt < 2; ++mt)
                #pragma unroll
                for (int r = 0; r < 4; ++r) {
                    int row = mt * 16 + quad * 4 + r;
                    if (row < nr)
                        out[(size_t)sRows[row] * 256 + colb] = acc[mt][si][r] + bias;
                }
        }
    }
}

extern "C" void kernel_launch(void* const* d_in, const int* in_sizes, int n_in,
                              void* d_out, int out_size, void* d_ws, size_t ws_size,
                              hipStream_t stream) {
    const float* state   = (const float*)d_in[0];
    const float* obs     = (const float*)d_in[1];
    const int*   cat_ids = (const int*)d_in[2];
    const float* obs_W   = (const float*)d_in[3];
    const float* obs_b   = (const float*)d_in[4];
    const float* state_W = (const float*)d_in[5];
    const float* state_b = (const float*)d_in[6];
    const float* l2_W    = (const float*)d_in[7];
    const float* l2_b    = (const float*)d_in[8];
    float* out = (float*)d_out;

    char* ws = (char*)d_ws;
    int* counts  = (int*)ws;
    int* rowsbuf = (int*)(ws + OFF_ROWS);
    unsigned short* p_obs  = (unsigned short*)(ws + OFF_POBS);
    unsigned short* p_stat = (unsigned short*)(ws + OFF_PSTAT);
    unsigned short* p_l2   = (unsigned short*)(ws + OFF_PL2);
    const int do_l2 = (ws_size >= NEED_L2) ? 1 : 0;

    int prep_blocks = C_N + 16 + 64 + (do_l2 ? 512 : 0);
    prep_kernel<<<dim3(prep_blocks), dim3(256), 0, stream>>>(
        cat_ids, obs_W, state_W, l2_W, counts, rowsbuf, p_obs, p_stat, p_l2, do_l2);

    fused_kernel<<<dim3(C_N, CAP / 32), dim3(512), 0, stream>>>(
        state, obs, obs_b, state_b, l2_W, l2_b, counts, rowsbuf,
        p_obs, p_stat, p_l2, do_l2, out);
}

// Round 8
// 98.204 us; speedup vs baseline: 1.0613x; 1.0613x over previous
//
#include <hip/hip_runtime.h>

// Problem constants (fixed by the reference)
constexpr int B_N   = 2048;
constexpr int C_N   = 32;
constexpr int SD    = 64;    // STATE_DIM
constexpr int EMB   = 256;
constexpr int OUTD  = 256;
constexpr int OBSD  = 512;
constexpr int XDIM  = 512;   // concat dim
constexpr int CAP   = 256;   // per-category row capacity (mean 64, ~96 at 4 sigma)

typedef __attribute__((ext_vector_type(8))) short bf16x8;
typedef __attribute__((ext_vector_type(4))) short bf16x4;
typedef __attribute__((ext_vector_type(4))) float f32x4;

// ws layout (bytes):
//   0        : int counts[32]
//   4096     : int rows[32][CAP]            (32 KB)
//   65536    : packed obs_W   bf16          (256 KB)
//   327680   : packed state_W bf16          (1 MB)
//   1376256  : packed l2_W    bf16          (8 MB)
constexpr size_t OFF_ROWS  = 4096;
constexpr size_t OFF_POBS  = 65536;
constexpr size_t OFF_PSTAT = 327680;
constexpr size_t OFF_PL2   = 1376256;
constexpr size_t NEED_L2   = OFF_PL2 + (size_t)C_N * XDIM * OUTD * 2;

__device__ __forceinline__ unsigned short bf_cvt(float f) {
    union { float f; unsigned u; } x; x.f = f;
    unsigned r = x.u + 0x7FFF + ((x.u >> 16) & 1);   // RNE
    return (unsigned short)(r >> 16);
}

// Fragment layout (B-operand of mfma_f32_16x16x32_bf16), per K-chunk of 32:
//   p[((chunk*16 + strip)*64 + lane)*8 + j] = W[chunk*32 + (lane>>4)*8 + j][strip*16 + (lane&15)]
__global__ __launch_bounds__(256) void prep_kernel(
    const int* __restrict__ cat_ids,
    const float* __restrict__ obs_W, const float* __restrict__ state_W,
    const float* __restrict__ l2_W,
    int* __restrict__ counts, int* __restrict__ rows,
    unsigned short* __restrict__ p_obs, unsigned short* __restrict__ p_state,
    unsigned short* __restrict__ p_l2, int do_l2) {
    const int bid = blockIdx.x;
    const int t = threadIdx.x;

    if (bid < C_N) {
        // ---- bucket for category c = bid ----
        __shared__ int cnt;
        __shared__ int list[CAP];
        if (t == 0) cnt = 0;
        __syncthreads();
        const int c = bid;
        for (int r = t; r < B_N; r += 256) {
            if (cat_ids[r] == c) {
                int s = atomicAdd(&cnt, 1);
                if (s < CAP) list[s] = r;
            }
        }
        __syncthreads();
        int n = min(cnt, CAP);
        for (int s = t; s < n; s += 256) rows[c * CAP + s] = list[s];
        if (t == 0) counts[c] = n;
        return;
    }

    // ---- pack one 32-row K-chunk of one weight matrix ----
    const float* src;
    unsigned short* dst;
    {
        int pb = bid - C_N;
        if (pb < 16) {                       // obs_W, chunk = pb
            src = obs_W + (size_t)pb * 32 * 256;
            dst = p_obs + (size_t)pb * 8192;
        } else if (pb < 80) {                // state_W: i = mat*2 + chunk
            int i = pb - 16;
            int mat = i >> 1, ch = i & 1;
            src = state_W + ((size_t)mat * SD + ch * 32) * 256;
            dst = p_state + (size_t)i * 8192;
        } else {                             // l2_W: i = mat*16 + chunk
            if (!do_l2) return;
            int i = pb - 80;
            int mat = i >> 4, ch = i & 15;
            src = l2_W + ((size_t)mat * XDIM + ch * 32) * 256;
            dst = p_l2 + (size_t)i * 8192;
        }
    }

    __shared__ __align__(16) unsigned short sW[32 * 264];   // 32 rows, pad 256->264
    #pragma unroll
    for (int i2 = 0; i2 < 8; ++i2) {
        int f = t + 256 * i2;                // float4 index in contiguous 32x256 block
        int row = f >> 6, c4 = f & 63;
        float4 v = ((const float4*)src)[f];
        unsigned short* d = &sW[row * 264 + c4 * 4];
        d[0] = bf_cvt(v.x); d[1] = bf_cvt(v.y); d[2] = bf_cvt(v.z); d[3] = bf_cvt(v.w);
    }
    __syncthreads();
    #pragma unroll
    for (int s4 = 0; s4 < 4; ++s4) {
        int slot = s4 * 256 + t;             // (strip,lane) slot, 1024 total
        int strip = slot >> 6, lane = slot & 63;
        int r0 = (lane >> 4) * 8, col = strip * 16 + (lane & 15);
        unsigned short v[8];
        #pragma unroll
        for (int j = 0; j < 8; ++j) v[j] = sW[(r0 + j) * 264 + col];
        *(bf16x8*)(dst + (size_t)slot * 8) = *(bf16x8*)v;
    }
}

// One block per (cat, 16-row tile). 512 threads = 8 waves; wave w owns col
// strips {2w, 2w+1}. All 16 MFMA rows are real (tile = MFMA M).
__global__ __launch_bounds__(512) void fused_kernel(
    const float* __restrict__ state, const float* __restrict__ obs,
    const float* __restrict__ obs_b, const float* __restrict__ state_b,
    const float* __restrict__ l2_W, const float* __restrict__ l2_b,
    const int* __restrict__ counts, const int* __restrict__ rows,
    const unsigned short* __restrict__ p_obs,
    const unsigned short* __restrict__ p_state,
    const unsigned short* __restrict__ p_l2, int has_pl2,
    float* __restrict__ out) {
    const int c = blockIdx.x;
    const int tile = blockIdx.y;
    const int n = counts[c];
    const int rbase = tile * 16;
    if (rbase >= n) return;
    const int nr = min(16, n - rbase);

    __shared__ __align__(16) unsigned short sAs[16 * 72];    // state rows (pad 64->72)
    __shared__ __align__(16) unsigned short sAo[16 * 520];   // obs rows (pad 512->520)
    __shared__ __align__(16) unsigned short sX[16 * 520];    // x rows (pad 512->520)
    __shared__ int sRows[16];

    const int t = threadIdx.x;
    const int w = t >> 6, l = t & 63;
    const int ml = l & 15, quad = l >> 4;
    const int* rowp = rows + c * CAP + rbase;

    // Stage row ids for the epilogue (visible after the post-gather barrier).
    if (t < 16) sRows[t] = (t < nr) ? rowp[t] : 0;

    // ---- Gather + fp32->bf16 (issued FIRST: these loads gate the barrier) ----
    {   // state: 16 rows x 16 float4 = 256 slots
        if (t < 256) {
            int i = t >> 4, c4 = t & 15;
            unsigned short vv[4] = {0, 0, 0, 0};
            if (i < nr) {
                int ridx = rowp[i];
                float4 v = ((const float4*)(state + (size_t)ridx * SD))[c4];
                vv[0] = bf_cvt(v.x); vv[1] = bf_cvt(v.y); vv[2] = bf_cvt(v.z); vv[3] = bf_cvt(v.w);
            }
            *(bf16x4*)&sAs[i * 72 + c4 * 4] = *(bf16x4*)vv;
        }
        #pragma unroll
        for (int i2 = 0; i2 < 4; ++i2) {     // obs: 16 rows x 128 float4 = 2048 slots
            int f = t + 512 * i2;
            int i = f >> 7, c4 = f & 127;
            unsigned short vv[4] = {0, 0, 0, 0};
            if (i < nr) {
                int ridx = rowp[i];
                float4 v = ((const float4*)(obs + (size_t)ridx * OBSD))[c4];
                vv[0] = bf_cvt(v.x); vv[1] = bf_cvt(v.y); vv[2] = bf_cvt(v.z); vv[3] = bf_cvt(v.w);
            }
            *(bf16x4*)&sAo[i * 520 + c4 * 4] = *(bf16x4*)vv;
        }
    }

    // ---- Prefetch b-fragments: phase-1 (all 4), phase-2 (first 6 chunks),
    //      AND phase-3 (first 6 chunks). All drain during gather/phases 1-2.
    const bf16x8* pb1 = (const bf16x8*)(p_state + (size_t)c * SD * 256);
    const bf16x8* pb2 = (const bf16x8*)p_obs;
    const bf16x8* pb3 = (const bf16x8*)p_l2 + (size_t)c * 16384;
    bf16x8 pf1[4], pf2[12], pf3[12];
    #pragma unroll
    for (int kk = 0; kk < 2; ++kk)
        #pragma unroll
        for (int si = 0; si < 2; ++si)
            pf1[kk * 2 + si] = pb1[(kk * 16 + w * 2 + si) * 64 + l];
    #pragma unroll
    for (int kk = 0; kk < 6; ++kk)
        #pragma unroll
        for (int si = 0; si < 2; ++si)
            pf2[kk * 2 + si] = pb2[(kk * 16 + w * 2 + si) * 64 + l];
    if (has_pl2) {
        #pragma unroll
        for (int kk = 0; kk < 6; ++kk)
            #pragma unroll
            for (int si = 0; si < 2; ++si)
                pf3[kk * 2 + si] = pb3[(kk * 16 + w * 2 + si) * 64 + l];
    }
    __syncthreads();

    // ---- Phase 1: state_emb = relu(A_s x state_W[c] + b)  (K=64: 2 chunks) ----
    {
        f32x4 acc[2];
        #pragma unroll
        for (int si = 0; si < 2; ++si) acc[si] = (f32x4){0.f, 0.f, 0.f, 0.f};
        #pragma unroll
        for (int kk = 0; kk < 2; ++kk) {
            bf16x8 a = *(const bf16x8*)&sAs[ml * 72 + kk * 32 + quad * 8];
            #pragma unroll
            for (int si = 0; si < 2; ++si)
                acc[si] = __builtin_amdgcn_mfma_f32_16x16x32_bf16(a, pf1[kk * 2 + si], acc[si], 0, 0, 0);
        }
        #pragma unroll
        for (int si = 0; si < 2; ++si) {
            int colb = (w * 2 + si) * 16 + ml;
            float bias = state_b[c * 256 + colb];
            #pragma unroll
            for (int r = 0; r < 4; ++r)
                sX[(quad * 4 + r) * 520 + colb] = bf_cvt(fmaxf(acc[si][r] + bias, 0.f));
        }
    }

    // ---- Phase 2: obs_emb = A_o x obs_W + b  (K=512: 16 chunks, ring depth 6) ----
    {
        f32x4 acc[2];
        #pragma unroll
        for (int si = 0; si < 2; ++si) acc[si] = (f32x4){0.f, 0.f, 0.f, 0.f};
        #pragma unroll
        for (int kk = 0; kk < 16; ++kk) {
            bf16x8 a = *(const bf16x8*)&sAo[ml * 520 + kk * 32 + quad * 8];
            #pragma unroll
            for (int si = 0; si < 2; ++si) {
                int slot = (kk % 6) * 2 + si;
                bf16x8 b = pf2[slot];
                if (kk < 10)
                    pf2[slot] = pb2[((kk + 6) * 16 + w * 2 + si) * 64 + l];
                acc[si] = __builtin_amdgcn_mfma_f32_16x16x32_bf16(a, b, acc[si], 0, 0, 0);
            }
        }
        #pragma unroll
        for (int si = 0; si < 2; ++si) {
            int colb = (w * 2 + si) * 16 + ml;
            float bias = obs_b[colb];
            #pragma unroll
            for (int r = 0; r < 4; ++r)
                sX[(quad * 4 + r) * 520 + 256 + colb] = bf_cvt(acc[si][r] + bias);
        }
    }
    __syncthreads();

    // ---- Phase 3: out = x @ l2_W[c] + b  (K=512: 16 chunks, ring depth 6;
    //      first 6 chunks prefetched long ago) ----
    {
        f32x4 acc[2];
        #pragma unroll
        for (int si = 0; si < 2; ++si) acc[si] = (f32x4){0.f, 0.f, 0.f, 0.f};
        if (has_pl2) {
            #pragma unroll
            for (int kk = 0; kk < 16; ++kk) {
                bf16x8 a = *(const bf16x8*)&sX[ml * 520 + kk * 32 + quad * 8];
                #pragma unroll
                for (int si = 0; si < 2; ++si) {
                    int slot = (kk % 6) * 2 + si;
                    bf16x8 b = pf3[slot];
                    if (kk < 10)
                        pf3[slot] = pb3[((kk + 6) * 16 + w * 2 + si) * 64 + l];
                    acc[si] = __builtin_amdgcn_mfma_f32_16x16x32_bf16(a, b, acc[si], 0, 0, 0);
                }
            }
        } else {
            for (int kk = 0; kk < 16; ++kk) {
                bf16x8 a = *(const bf16x8*)&sX[ml * 520 + kk * 32 + quad * 8];
                #pragma unroll
                for (int si = 0; si < 2; ++si) {
                    const float* wsrc = l2_W + ((size_t)c * XDIM + kk * 32 + quad * 8) * 256
                                        + (w * 2 + si) * 16 + ml;
                    bf16x8 b;
                    #pragma unroll
                    for (int j = 0; j < 8; ++j) b[j] = (short)bf_cvt(wsrc[j * 256]);
                    acc[si] = __builtin_amdgcn_mfma_f32_16x16x32_bf16(a, b, acc[si], 0, 0, 0);
                }
            }
        }
        #pragma unroll
        for (int si = 0; si < 2; ++si) {
            int colb = (w * 2 + si) * 16 + ml;
            float bias = l2_b[c * 256 + colb];
            #pragma unroll
            for (int r = 0; r < 4; ++r) {
                int row = quad * 4 + r;
                if (row < nr)
                    out[(size_t)sRows[row] * 256 + colb] = acc[si][r] + bias;
            }
        }
    }
}

extern "C" void kernel_launch(void* const* d_in, const int* in_sizes, int n_in,
                              void* d_out, int out_size, void* d_ws, size_t ws_size,
                              hipStream_t stream) {
    const float* state   = (const float*)d_in[0];
    const float* obs     = (const float*)d_in[1];
    const int*   cat_ids = (const int*)d_in[2];
    const float* obs_W   = (const float*)d_in[3];
    const float* obs_b   = (const float*)d_in[4];
    const float* state_W = (const float*)d_in[5];
    const float* state_b = (const float*)d_in[6];
    const float* l2_W    = (const float*)d_in[7];
    const float* l2_b    = (const float*)d_in[8];
    float* out = (float*)d_out;

    char* ws = (char*)d_ws;
    int* counts  = (int*)ws;
    int* rowsbuf = (int*)(ws + OFF_ROWS);
    unsigned short* p_obs  = (unsigned short*)(ws + OFF_POBS);
    unsigned short* p_stat = (unsigned short*)(ws + OFF_PSTAT);
    unsigned short* p_l2   = (unsigned short*)(ws + OFF_PL2);
    const int do_l2 = (ws_size >= NEED_L2) ? 1 : 0;

    int prep_blocks = C_N + 16 + 64 + (do_l2 ? 512 : 0);
    prep_kernel<<<dim3(prep_blocks), dim3(256), 0, stream>>>(
        cat_ids, obs_W, state_W, l2_W, counts, rowsbuf, p_obs, p_stat, p_l2, do_l2);

    fused_kernel<<<dim3(C_N, CAP / 16), dim3(512), 0, stream>>>(
        state, obs, obs_b, state_b, l2_W, l2_b, counts, rowsbuf,
        p_obs, p_stat, p_l2, do_l2, out);
}